// Round 14
// baseline (199.717 us; speedup 1.0000x reference)
//
#include <hip/hip_runtime.h>
#include <stdint.h>

#define A_N 9
#define H_N 50
#define W_N 76
#define HW_N (H_N * W_N)      // 3800
#define N_PROP (A_N * HW_N)   // 34200
#define B_N 4
#define PRE_NMS 4000
#define POST_NMS 300
#define NMS_TH 0.7f
#define SORT_N 4096
#define MASK_WORDS 64
#define CAND_MAX 5120
#define NBINS 4096
#define NPAIR 32
#define NLW 5
#define NDELTA 6
#define DEC_BLKS ((N_PROP + 255) / 256)   // 134

// ---------------------------------------------------------------------------
// Kernel A: decode + keys, WIDE grid (r10: narrow fused front was
// latency-bound on 4 CUs). No histogram — mid_kernel rebuilds from keys.
// ---------------------------------------------------------------------------
__global__ __launch_bounds__(256) void decode_kernel(
    const float* __restrict__ scores,
    const float* __restrict__ deltas,
    const float* __restrict__ im_info,
    const float* __restrict__ anchors,
    float4* __restrict__ boxes,
    unsigned long long* __restrict__ keys) {
#pragma clang fp contract(off)
    int tid = threadIdx.x;
    int b = blockIdx.y;
    int r = blockIdx.x * 256 + tid;
    if (r >= N_PROP) return;

    int a = r / HW_N;          // fixed across a wave
    int hw = r - a * HW_N;     // consecutive across lanes
    int hy = hw / W_N;
    int wx = hw - hy * W_N;

    float sx = (float)wx * 16.0f;
    float sy = (float)hy * 16.0f;
    float ax1 = anchors[a * 4 + 0] + sx;
    float ay1 = anchors[a * 4 + 1] + sy;
    float ax2 = anchors[a * 4 + 2] + sx;
    float ay2 = anchors[a * 4 + 3] + sy;
    float aw = ax2 - ax1 + 1.0f;
    float ah = ay2 - ay1 + 1.0f;
    float cx = ax1 + 0.5f * aw;
    float cy = ay1 + 0.5f * ah;

    const float* db = deltas + ((size_t)b * 36 + (size_t)a * 4) * HW_N + hw;
    float d0 = db[0];
    float d1 = db[HW_N];
    float d2 = db[2 * HW_N];
    float d3 = db[3 * HW_N];

    float pcx = d0 * aw + cx;
    float pcy = d1 * ah + cy;
    float pw  = expf(d2) * aw;
    float ph  = expf(d3) * ah;

    float x1 = pcx - 0.5f * pw;
    float y1 = pcy - 0.5f * ph;
    float x2 = pcx + 0.5f * pw;
    float y2 = pcy + 0.5f * ph;

    float xhi = im_info[b * 3 + 1] - 1.0f;
    float yhi = im_info[b * 3 + 0] - 1.0f;
    x1 = fminf(fmaxf(x1, 0.0f), xhi);
    y1 = fminf(fmaxf(y1, 0.0f), yhi);
    x2 = fminf(fmaxf(x2, 0.0f), xhi);
    y2 = fminf(fmaxf(y2, 0.0f), yhi);

    boxes[(size_t)b * N_PROP + r] = make_float4(x1, y1, x2, y2);  // a-major

    float s = scores[((size_t)b * A_N + a) * HW_N + hw];
    unsigned f = __float_as_uint(s);
    unsigned sk = f ^ ((f & 0x80000000u) ? 0xFFFFFFFFu : 0x80000000u);
    unsigned n_ref = (unsigned)(hw * A_N + a);
    unsigned long long key = ((unsigned long long)sk << 32) | (unsigned)(~n_ref);
    keys[(size_t)b * N_PROP + r] = key;
}

// ---------------------------------------------------------------------------
// Kernel B' (mid): LDS histogram + findT + compact, one block per batch.
// Single histogram (r12 form): r13's 4x replication REGRESSED ~2.4us
// (same-address LDS atomics were not the bottleneck; init+merge overhead).
// ---------------------------------------------------------------------------
__global__ __launch_bounds__(1024) void mid_kernel(
    const unsigned long long* __restrict__ keys,
    unsigned* __restrict__ cnt,
    unsigned long long* __restrict__ cand) {
    __shared__ unsigned hist[NBINS];
    __shared__ int Tlds;
    __shared__ unsigned cntL;
    const int b = blockIdx.x;
    const int tid = threadIdx.x;

    for (int i = tid; i < NBINS; i += 1024) hist[i] = 0u;
    if (tid == 0) cntL = 0u;
    __syncthreads();

    for (int it = 0; it < (N_PROP + 1023) / 1024; ++it) {
        int n = it * 1024 + tid;
        if (n < N_PROP) {
            unsigned long long k = keys[(size_t)b * N_PROP + n];
            atomicAdd(&hist[(unsigned)(k >> 52)], 1u);
        }
    }
    __syncthreads();

    // ---- findT (wave 0) ----
    if (tid < 64) {
        int lane = tid;
        unsigned gsum = 0;
        for (int j = 0; j < 64; ++j) gsum += hist[lane * 64 + j];
        unsigned s = gsum;
        for (int d = 1; d < 64; d <<= 1) {
            unsigned t = (unsigned)__shfl_down((int)s, d);
            if (lane + d < 64) s += t;
        }
        unsigned long long bal = __ballot(s >= PRE_NMS);
        int gstar = 63 - __builtin_clzll(bal);
        unsigned after = (gstar < 63)
            ? (unsigned)__builtin_amdgcn_readlane((int)s, gstar + 1) : 0u;
        unsigned R = PRE_NMS - after;
        unsigned s2 = hist[gstar * 64 + lane];
        for (int d = 1; d < 64; d <<= 1) {
            unsigned t = (unsigned)__shfl_down((int)s2, d);
            if (lane + d < 64) s2 += t;
        }
        unsigned long long bal2 = __ballot(s2 >= R);
        int j = 63 - __builtin_clzll(bal2);
        if (lane == 0) Tlds = gstar * 64 + j;
    }
    __syncthreads();

    // ---- compact (wave-aggregated LDS atomic) ----
    const int Tb = Tlds;
    for (int it = 0; it < (N_PROP + 1023) / 1024; ++it) {
        int n = it * 1024 + tid;
        bool pred = false;
        unsigned long long k = 0ull;
        if (n < N_PROP) {
            k = keys[(size_t)b * N_PROP + n];
            pred = ((int)(unsigned)(k >> 52) >= Tb);
        }
        unsigned long long m = __ballot(pred);
        if (m) {
            int lane = tid & 63;
            int lead = __ffsll((unsigned long long)m) - 1;
            unsigned base = 0;
            if (lane == lead) base = atomicAdd(&cntL, (unsigned)__popcll(m));
            base = __shfl((int)base, lead);
            if (pred) {
                unsigned pos = base + (unsigned)__popcll(m & ((1ull << lane) - 1ull));
                if (pos < CAND_MAX) cand[(size_t)b * CAND_MAX + pos] = k;
            }
        }
    }
    __syncthreads();
    if (tid == 0) cnt[b] = cntL;
}

// ---------------------------------------------------------------------------
// Kernel D: exact rank by pairwise count (unchanged from r8).
// ---------------------------------------------------------------------------
__global__ __launch_bounds__(256) void rank_scatter_kernel(
    const unsigned long long* __restrict__ cand,
    const unsigned* __restrict__ cnt,
    const float4* __restrict__ boxes,
    float4* __restrict__ sortedBoxes) {
    __shared__ unsigned long long sk[256];
    int b = blockIdx.y;
    int tid = threadIdx.x;
    int ci = blockIdx.x * 64 + (tid >> 2);
    int q = tid & 3;
    int mc = (int)min(cnt[b], (unsigned)CAND_MAX);
    unsigned long long my = (ci < mc) ? cand[(size_t)b * CAND_MAX + ci] : 0ull;
    int rank = 0;
    int nt = (mc + 255) >> 8;
    for (int t = 0; t < nt; ++t) {
        int j = t * 256 + tid;
        sk[tid] = (j < mc) ? cand[(size_t)b * CAND_MAX + j] : 0ull;
        __syncthreads();
#pragma unroll 16
        for (int c = 0; c < 64; ++c) {
            int cc = q * 64 + ((c + q * 17) & 63);  // stagger: avoid 4-way bank conflict
            rank += (sk[cc] > my) ? 1 : 0;
        }
        __syncthreads();
    }
    rank += __shfl_xor(rank, 1);
    rank += __shfl_xor(rank, 2);
    if (q == 0 && ci < mc && rank < PRE_NMS) {
        unsigned n_ref = ~(unsigned)(my & 0xFFFFFFFFull);
        unsigned a = n_ref % A_N;
        unsigned hw = n_ref / A_N;
        sortedBoxes[(size_t)b * SORT_N + rank] =
            boxes[(size_t)b * N_PROP + a * HW_N + hw];
    }
    if (q == 1) {
        int pi = blockIdx.x * 64 + (tid >> 2);
        if (pi >= PRE_NMS && pi < SORT_N)
            sortedBoxes[(size_t)b * SORT_N + pi] = make_float4(0.f, 0.f, 0.f, 0.f);
    }
}

// ---------------------------------------------------------------------------
// Kernel E: suppression bitmask, upper-triangle-only grid.
// NEW: near-diagonal tiles (cc-rc < 6) additionally written BIT-TRANSPOSED
// to `trans[b][rc][delta][lane j]` = column-j-over-rows word, via a 64-ballot
// loop (~640cy on ~1/13 of waves — hidden at full occupancy). This lets the
// scan's decider replace every readlane row-fetch / OR-reduction with ONE
// ballot (see Kernel F).
// ---------------------------------------------------------------------------
__global__ __launch_bounds__(256) void iou_mask_kernel(
    const float4* __restrict__ sortedBoxes,
    unsigned long long* __restrict__ colmaj,
    unsigned long long* __restrict__ rowmaj,
    unsigned long long* __restrict__ trans) {
#pragma clang fp contract(off)
    int b = blockIdx.y;
    int wv = threadIdx.x >> 6;
    int t = threadIdx.x & 63;
    int k = blockIdx.x * 4 + wv;          // 0..2079, upper-tri linear index
    int rc = 0;
    while (k >= 64 - rc) { k -= 64 - rc; ++rc; }
    int cc = rc + k;

    __shared__ float4 colb[4][64];
    colb[wv][t] = sortedBoxes[(size_t)b * SORT_N + cc * 64 + t];
    __syncthreads();

    int r = rc * 64 + t;
    float4 rb = sortedBoxes[(size_t)b * SORT_N + r];
    float rarea = (rb.z - rb.x) * (rb.w - rb.y);
    unsigned long long word = 0ull;
    for (int c = 0; c < 64; ++c) {
        int j = cc * 64 + c;
        float4 cb = colb[wv][c];
        float carea = (cb.z - cb.x) * (cb.w - cb.y);
        float ltx = fmaxf(rb.x, cb.x);
        float lty = fmaxf(rb.y, cb.y);
        float rbx = fminf(rb.z, cb.z);
        float rby = fminf(rb.w, cb.w);
        float iw = fmaxf(rbx - ltx, 0.0f);
        float ih = fmaxf(rby - lty, 0.0f);
        float inter = iw * ih;
        float iou = inter / (rarea + carea - inter + 1e-9f);
        if (iou > NMS_TH && j > r) word |= (1ull << c);
    }
    colmaj[((size_t)b * MASK_WORDS + cc) * SORT_N + r] = word;   // coalesced
    rowmaj[((size_t)b * SORT_N + r) * MASK_WORDS + cc] = word;   // scatter

    int delta = cc - rc;
    if (delta < NDELTA) {
        // bit-transpose the 64x64 tile across the wave: lane j gets column j
        unsigned long long tw = 0ull;
        for (int j = 0; j < 64; ++j) {
            unsigned long long bal = __ballot(((word >> j) & 1ull) != 0ull);
            if (t == j) tw = bal;
        }
        trans[(((size_t)b * MASK_WORDS + rc) * NDELTA + delta) * 64 + t] = tw;
    }
}

// ---------------------------------------------------------------------------
// Kernel F: MULTI-WAVE greedy scan, RAW-BARRIER PIPELINED, BALLOT-ALGEBRA.
// r13 evidence: L2-warm replay also ~49us -> scan is on-chip serial-chain
// bound (VALUBusy 6%/CU). All near-diagonal tiles are now TRANSPOSED
// (lane j = column j over the group's rows), so:
//   row-fetch in greedy chain:  d = ballot((dAT >> bit) & 1)      (~15cy)
//   every OR-reduction:         bal_nz = ballot((tileT & alive)!=0) (~10cy)
// replacing readlane waterfalls (~50cy) and 14-op DPP chains (~100cy).
// Identical set algebra -> bit-exact. Loaders/rem/kept logic unchanged.
// ---------------------------------------------------------------------------
__device__ __forceinline__ unsigned long long bal_nz(unsigned long long tileT,
                                                     unsigned long long alive) {
    return __ballot((tileT & alive) != 0ull);
}

__device__ __forceinline__ void block_sync() {
    asm volatile("s_waitcnt lgkmcnt(0)" ::: "memory");   // LDS visibility, NO vmcnt drain
    __builtin_amdgcn_s_barrier();
    asm volatile("" ::: "memory");
}

#define GLOAD(dst, addr) \
    asm volatile("global_load_dwordx2 %0, %1, off" : "=v"(dst) : "v"(addr))
#define WAITV0 asm volatile("s_waitcnt vmcnt(0)" ::: "memory")
#define SCHED0 __builtin_amdgcn_sched_barrier(0)

// tile t of pair P (transposed storage): t<6 -> group 2P, delta t;
// t>=6 -> group 2P+1, delta t-6. Valid iff group+delta < 64.
#define TRG(P, t)  ((t) < 6 ? 2 * (P) : 2 * (P) + 1)
#define TRD(P, t)  ((t) < 6 ? (t) : (t) - 6)
#define TRVAL(P, t) (TRG(P, t) + TRD(P, t) < 64)
#define TR_ADDR(P, t) \
    (TR + (((size_t)TRG(P, t) * NDELTA + (TRVAL(P, t) ? TRD(P, t) : 0)) << 6) + lane)

#define ISSUE_PAIR(P)                                                          \
    do {                                                                       \
        pf_vmask = 0u;                                                         \
        GLOAD(pf0,  TR_ADDR(P, 0));  if (TRVAL(P, 0))  pf_vmask |= 1u << 0;    \
        GLOAD(pf1,  TR_ADDR(P, 1));  if (TRVAL(P, 1))  pf_vmask |= 1u << 1;    \
        GLOAD(pf2,  TR_ADDR(P, 2));  if (TRVAL(P, 2))  pf_vmask |= 1u << 2;    \
        GLOAD(pf3,  TR_ADDR(P, 3));  if (TRVAL(P, 3))  pf_vmask |= 1u << 3;    \
        GLOAD(pf4,  TR_ADDR(P, 4));  if (TRVAL(P, 4))  pf_vmask |= 1u << 4;    \
        GLOAD(pf5,  TR_ADDR(P, 5));  if (TRVAL(P, 5))  pf_vmask |= 1u << 5;    \
        GLOAD(pf6,  TR_ADDR(P, 6));  if (TRVAL(P, 6))  pf_vmask |= 1u << 6;    \
        GLOAD(pf7,  TR_ADDR(P, 7));  if (TRVAL(P, 7))  pf_vmask |= 1u << 7;    \
        GLOAD(pf8,  TR_ADDR(P, 8));  if (TRVAL(P, 8))  pf_vmask |= 1u << 8;    \
        GLOAD(pf9,  TR_ADDR(P, 9));  if (TRVAL(P, 9))  pf_vmask |= 1u << 9;    \
        GLOAD(pf10, TR_ADDR(P, 10)); if (TRVAL(P, 10)) pf_vmask |= 1u << 10;   \
    } while (0)

#define NEXTROW2(rk)                                                           \
    int rk;                                                                    \
    {                                                                          \
        if (xA) { int bb_ = __builtin_ctzll(xA); xA &= xA - 1; rk = baseA + bb_; } \
        else if (xB) { int bb_ = __builtin_ctzll(xB); xB &= xB - 1; rk = baseB + bb_; } \
        else rk = rpad;                                                        \
    }

__global__ __launch_bounds__(512, 1) void nms_scan_kernel(
    const unsigned long long* __restrict__ trans,
    const unsigned long long* __restrict__ rowmaj,
    const float4* __restrict__ sortedBoxes,
    float* __restrict__ out) {
    int b = blockIdx.x;
    int tid = threadIdx.x;
    int lane = tid & 63;
    int wv = tid >> 6;   // 0 decider, 1 prefetch, 2 helper, 3..7 loaders
    const unsigned long long* TR = trans + (size_t)b * MASK_WORDS * NDELTA * 64;
    const unsigned long long* R = rowmaj + (size_t)b * SORT_N * MASK_WORDS;

    __shared__ int kept[POST_NMS];
    __shared__ unsigned remW[MASK_WORDS][2];            // [word][lo,hi]
    __shared__ unsigned long long aliveLds[MASK_WORDS];
    __shared__ unsigned long long ring[4][11][64];      // tile ring, slot = pair&3
    __shared__ unsigned long long car2[2][2];           // helper d2 carries, slot = pair&1
    __shared__ int doneLds;
    __shared__ int kcntLds;

    if (tid < MASK_WORDS) { remW[tid][0] = 0u; remW[tid][1] = 0u; aliveLds[tid] = 0ull; }
    if (tid < 4) car2[tid >> 1][tid & 1] = 0ull;
    if (tid == 0) { doneLds = 0; kcntLds = 0; }

    unsigned long long pf0=0,pf1=0,pf2=0,pf3=0,pf4=0,pf5=0,pf6=0,pf7=0,pf8=0,pf9=0,pf10=0;
    unsigned pf_vmask = 0u;
    bool pf_have = false;
    unsigned long long gp0=0,gp1=0,gp2=0,gp3=0,gp4=0,gp5=0,gp6=0,gp7=0;
    bool ld_valid = false;

    // ---- prologue: stage pair 0 synchronously, issue pair 1 (in flight) ----
    if (wv == 1) {
        for (int t = 0; t < 11; ++t) {
            unsigned long long v = TRVAL(0, t)
                ? TR[(((size_t)TRG(0, t)) * NDELTA + TRD(0, t)) * 64 + lane] : 0ull;
            ring[0][t][lane] = v;
        }
        ISSUE_PAIR(1);
        pf_have = true;
    }
    block_sync();

    unsigned long long carA = 0ull, carB = 0ull;   // decider: d1 carries (pair q-1 -> q)
    int kcnt = 0;

    for (int q = 0; q < NPAIR; ++q) {
        if (wv == 0) {
            // ---------------- decider: pair q (all tiles TRANSPOSED) --------
            int A = 2 * q, Bg = A + 1, slot = q & 3;
            unsigned long long dA  = ring[slot][0][lane];
            unsigned long long tA1 = ring[slot][1][lane];
            unsigned long long tA2 = ring[slot][2][lane];
            unsigned long long tA3 = ring[slot][3][lane];
            unsigned long long dB  = ring[slot][6][lane];
            unsigned long long tB1 = ring[slot][7][lane];
            unsigned long long tB2 = ring[slot][8][lane];
            unsigned long long remA =
                ((unsigned long long)remW[A][1] << 32) | (unsigned long long)remW[A][0];
            unsigned long long remB =
                ((unsigned long long)remW[Bg][1] << 32) | (unsigned long long)remW[Bg][0];
            unsigned long long h2A = car2[q & 1][0];
            unsigned long long h2B = car2[q & 1][1];
            bool hit = false;
            unsigned long long aliveA = 0ull, aliveB = 0ull;
            unsigned long long pend = ~(remA | carA | h2A);
            while (pend) {
                int bit = __builtin_ctzll(pend);
                if (lane == 0) kept[kcnt] = (A << 6) + bit;
                ++kcnt;
                aliveA |= 1ull << bit;
                if (kcnt == POST_NMS) { hit = true; break; }
                unsigned long long d = __ballot(((dA >> bit) & 1ull) != 0ull);
                pend &= ~(d | (1ull << bit));
            }
            if (!hit) {
                unsigned long long nA1 = bal_nz(tA1, aliveA);
                pend = ~(remB | carB | h2B | nA1);
                while (pend) {
                    int bit = __builtin_ctzll(pend);
                    if (lane == 0) kept[kcnt] = (Bg << 6) + bit;
                    ++kcnt;
                    aliveB |= 1ull << bit;
                    if (kcnt == POST_NMS) { hit = true; break; }
                    unsigned long long d = __ballot(((dB >> bit) & 1ull) != 0ull);
                    pend &= ~(d | (1ull << bit));
                }
            }
            carA = bal_nz(tA2, aliveA) | bal_nz(tB1, aliveB);
            carB = bal_nz(tA3, aliveA) | bal_nz(tB2, aliveB);
            if (lane == 0) {
                aliveLds[A]  = aliveA;
                aliveLds[Bg] = aliveB;
                kcntLds = kcnt;
                if (hit) doneLds = 1;
            }
        } else if (wv == 1) {
            // ---------------- prefetch: write pair q+1, issue pair q+2 ------
            if (pf_have) {
                WAITV0;
                SCHED0;
                int wp = q + 1;
                if (wp < NPAIR) {
                    int ws = wp & 3;
                    ring[ws][0][lane]  = (pf_vmask & (1u << 0))  ? pf0  : 0ull;
                    ring[ws][1][lane]  = (pf_vmask & (1u << 1))  ? pf1  : 0ull;
                    ring[ws][2][lane]  = (pf_vmask & (1u << 2))  ? pf2  : 0ull;
                    ring[ws][3][lane]  = (pf_vmask & (1u << 3))  ? pf3  : 0ull;
                    ring[ws][4][lane]  = (pf_vmask & (1u << 4))  ? pf4  : 0ull;
                    ring[ws][5][lane]  = (pf_vmask & (1u << 5))  ? pf5  : 0ull;
                    ring[ws][6][lane]  = (pf_vmask & (1u << 6))  ? pf6  : 0ull;
                    ring[ws][7][lane]  = (pf_vmask & (1u << 7))  ? pf7  : 0ull;
                    ring[ws][8][lane]  = (pf_vmask & (1u << 8))  ? pf8  : 0ull;
                    ring[ws][9][lane]  = (pf_vmask & (1u << 9))  ? pf9  : 0ull;
                    ring[ws][10][lane] = (pf_vmask & (1u << 10)) ? pf10 : 0ull;
                }
                pf_have = false;
            }
            int ip = q + 2;
            if (ip < NPAIR) {
                ISSUE_PAIR(ip);
                pf_have = true;
            }
        } else if (wv == 2) {
            // ---------------- helper: pair p=q-1 d2 carries -> pair q+1 -----
            if (q >= 1) {
                int p = q - 1, sp = p & 3;
                unsigned long long aA = aliveLds[2 * p];
                unsigned long long aB = aliveLds[2 * p + 1];
                unsigned long long tA4 = ring[sp][4][lane];
                unsigned long long tA5 = ring[sp][5][lane];
                unsigned long long tB3 = ring[sp][9][lane];
                unsigned long long tB4 = ring[sp][10][lane];
                unsigned long long c0 = bal_nz(tA4, aA) | bal_nz(tB3, aB);
                unsigned long long c1 = bal_nz(tA5, aA) | bal_nz(tB4, aB);
                if (lane == 0) {
                    car2[(q + 1) & 1][0] = c0;
                    car2[(q + 1) & 1][1] = c1;
                }
            }
        } else {
            // ---------------- loaders: fold prev batch, issue pair q-1 ------
            if (ld_valid) {
                WAITV0;
                SCHED0;
                unsigned long long acc =
                    ((gp0 | gp1) | (gp2 | gp3)) | ((gp4 | gp5) | (gp6 | gp7));
                unsigned lo = (unsigned)acc, hi = (unsigned)(acc >> 32);
                if (lo) atomicOr(&remW[lane][0], lo);
                if (hi) atomicOr(&remW[lane][1], hi);
                ld_valid = false;
            }
            if (q >= 1) {
                int p = q - 1, gA = 2 * p, gB = 2 * p + 1;
                unsigned long long aA = aliveLds[gA];
                unsigned long long aB = aliveLds[gB];
                int k = wv - 3;                       // 0..NLW-1
                unsigned long long below = (1ull << lane) - 1ull;
                bool inA = (aA >> lane) & 1ull;
                bool inB = (aB >> lane) & 1ull;
                int posA = (int)__popcll(aA & below);
                int posB = (int)__popcll(aA) + (int)__popcll(aB & below);
                unsigned long long mA = __ballot(inA && (posA % NLW) == k);
                unsigned long long mB = __ballot(inB && (posB % NLW) == k);
                if (mA | mB) {
                    int baseA = gA << 6, baseB = gB << 6;
                    unsigned long long xA = mA, xB = mB;
                    int rpad = mA ? (baseA + __builtin_ctzll(mA))
                                  : (baseB + __builtin_ctzll(mB));
                    NEXTROW2(r0) NEXTROW2(r1) NEXTROW2(r2) NEXTROW2(r3)
                    NEXTROW2(r4) NEXTROW2(r5) NEXTROW2(r6) NEXTROW2(r7)
                    const unsigned long long* Rb = R + lane;
                    GLOAD(gp0, Rb + (size_t)r0 * MASK_WORDS);
                    GLOAD(gp1, Rb + (size_t)r1 * MASK_WORDS);
                    GLOAD(gp2, Rb + (size_t)r2 * MASK_WORDS);
                    GLOAD(gp3, Rb + (size_t)r3 * MASK_WORDS);
                    GLOAD(gp4, Rb + (size_t)r4 * MASK_WORDS);
                    GLOAD(gp5, Rb + (size_t)r5 * MASK_WORDS);
                    GLOAD(gp6, Rb + (size_t)r6 * MASK_WORDS);
                    GLOAD(gp7, Rb + (size_t)r7 * MASK_WORDS);
                    ld_valid = true;
                    // overflow rows (>8 for this wave): rare, serial
                    unsigned long long ovf = 0ull;
                    while (xA) {
                        int bb = __builtin_ctzll(xA); xA &= xA - 1;
                        ovf |= Rb[(size_t)(baseA + bb) * MASK_WORDS];
                    }
                    while (xB) {
                        int bb = __builtin_ctzll(xB); xB &= xB - 1;
                        ovf |= Rb[(size_t)(baseB + bb) * MASK_WORDS];
                    }
                    if (ovf) {
                        unsigned lo = (unsigned)ovf, hi = (unsigned)(ovf >> 32);
                        if (lo) atomicOr(&remW[lane][0], lo);
                        if (hi) atomicOr(&remW[lane][1], hi);
                    }
                }
            }
        }
        block_sync();
        if (doneLds) break;
    }

    WAITV0;             // drain any in-flight asm loads before ending
    __syncthreads();

    int kc = kcntLds;   // last write barrier-ordered before every exit path
    for (int r = tid; r < POST_NMS; r += 512) {
        float* o = out + ((size_t)b * POST_NMS + r) * 5;
        float4 bx = make_float4(0.f, 0.f, 0.f, 0.f);
        if (r < kc) bx = sortedBoxes[(size_t)b * SORT_N + kept[r]];
        o[0] = (float)b;
        o[1] = bx.x;
        o[2] = bx.y;
        o[3] = bx.z;
        o[4] = bx.w;
    }
}

// ---------------------------------------------------------------------------
extern "C" void kernel_launch(void* const* d_in, const int* in_sizes, int n_in,
                              void* d_out, int out_size, void* d_ws, size_t ws_size,
                              hipStream_t stream) {
    const float* scores  = (const float*)d_in[0];
    const float* deltas  = (const float*)d_in[1];
    const float* im_info = (const float*)d_in[2];
    const float* anchors = (const float*)d_in[3];
    float* out = (float*)d_out;

    char* ws = (char*)d_ws;
    size_t off = 0;
    float4* boxes = (float4*)(ws + off);
    off += (size_t)B_N * N_PROP * sizeof(float4);
    off = (off + 255) & ~(size_t)255;
    unsigned long long* keys = (unsigned long long*)(ws + off);
    off += (size_t)B_N * N_PROP * sizeof(unsigned long long);
    off = (off + 255) & ~(size_t)255;
    float4* sortedBoxes = (float4*)(ws + off);
    off += (size_t)B_N * SORT_N * sizeof(float4);
    off = (off + 255) & ~(size_t)255;
    unsigned long long* colmaj = (unsigned long long*)(ws + off);
    off += (size_t)B_N * MASK_WORDS * SORT_N * sizeof(unsigned long long);
    off = (off + 255) & ~(size_t)255;
    unsigned long long* rowmaj = (unsigned long long*)(ws + off);
    off += (size_t)B_N * SORT_N * MASK_WORDS * sizeof(unsigned long long);
    off = (off + 255) & ~(size_t)255;
    unsigned long long* trans = (unsigned long long*)(ws + off);
    off += (size_t)B_N * MASK_WORDS * NDELTA * 64 * sizeof(unsigned long long);
    off = (off + 255) & ~(size_t)255;
    unsigned long long* cand = (unsigned long long*)(ws + off);
    off += (size_t)B_N * CAND_MAX * sizeof(unsigned long long);
    off = (off + 255) & ~(size_t)255;
    unsigned* cnt = (unsigned*)(ws + off);
    off += (size_t)B_N * sizeof(unsigned);

    decode_kernel<<<dim3(DEC_BLKS, B_N), 256, 0, stream>>>(
        scores, deltas, im_info, anchors, boxes, keys);
    mid_kernel<<<B_N, 1024, 0, stream>>>(keys, cnt, cand);
    rank_scatter_kernel<<<dim3(CAND_MAX / 64, B_N), 256, 0, stream>>>(
        cand, cnt, boxes, sortedBoxes);
    iou_mask_kernel<<<dim3(520, B_N), 256, 0, stream>>>(
        sortedBoxes, colmaj, rowmaj, trans);
    nms_scan_kernel<<<B_N, 512, 0, stream>>>(trans, rowmaj, sortedBoxes, out);
}